// Round 12
// baseline (320.205 us; speedup 1.0000x reference)
//
#include <hip/hip_runtime.h>
#include <math.h>

namespace {
constexpr int kT = 8, kL = 8, kN = 500, kD = 64, kK = 12;
constexpr int kLN  = kL * kN;        // 4000
constexpr int kTLN = kT * kL * kN;   // 32000
constexpr int kBUF = kTLN * kD;      // 2,048,000 floats
constexpr int XS = 68;               // padded LDS stride for X tiles
constexpr int EVR = 16;              // evo rows per block -> 250 blocks
}

__device__ __forceinline__ float sigf(float v) { return 1.f / (1.f + __expf(-v)); }

// Overflow-safe fast tanh: one v_exp instead of libm tanhf's long sequence.
__device__ __forceinline__ float tanh_fast(float v) {
    float e = __expf(-2.f * fabsf(v));
    float t = (1.f - e) / (1.f + e);
    return copysignf(t, v);
}

// 16-lane allreduce (sum) entirely on the VALU pipe via DPP — no DS ops.
// (validated R4: scorewd VALUBusy 53->65%, total -20us)
__device__ __forceinline__ float row_allreduce16(float v) {
    v += __int_as_float(__builtin_amdgcn_update_dpp(
            0, __float_as_int(v), 0xB1, 0xf, 0xf, true));   // quad_perm [1,0,3,2]
    v += __int_as_float(__builtin_amdgcn_update_dpp(
            0, __float_as_int(v), 0x4E, 0xf, 0xf, true));   // quad_perm [2,3,0,1]
    v += __int_as_float(__builtin_amdgcn_update_dpp(
            0, __float_as_int(v), 0x124, 0xf, 0xf, true));  // row_ror:4
    v += __int_as_float(__builtin_amdgcn_update_dpp(
            0, __float_as_int(v), 0x128, 0xf, 0xf, true));  // row_ror:8
    return v;
}

// Stage a 64x64 f32 tile (global row stride 64) into LDS (stride XS); rows clamped to M.
__device__ __forceinline__ void stage_x(const float* __restrict__ src, float* lds,
                                        int row0, int M) {
    int r  = threadIdx.x >> 4;
    int c4 = (threadIdx.x & 15) << 2;
#pragma unroll
    for (int i = 0; i < 4; ++i) {
        int rr  = r + 16 * i;
        int row = row0 + rr;
        row = row < M ? row : M - 1;
        float4 v = *reinterpret_cast<const float4*>(src + (size_t)row * 64 + c4);
        *reinterpret_cast<float4*>(lds + rr * XS + c4) = v;
    }
}

// Stage K x 64 weight (row-major) into LDS, stride 64.
template <int K>
__device__ __forceinline__ void stage_w(const float* __restrict__ w, float* lds) {
    const float4* s = reinterpret_cast<const float4*>(w);
    float4* d = reinterpret_cast<float4*>(lds);
#pragma unroll
    for (int i = 0; i < K / 16; ++i)
        d[threadIdx.x + 256 * i] = s[threadIdx.x + 256 * i];
}

// acc[i] += row(4*rblk+i) of Xtile @ W[:, 4*cblk..+3], K=64; W from global
// (L1-resident). Splits traffic: x on the DS pipe, w on the VMEM pipe.
__device__ __forceinline__ void gemm_core_gw(const float* ldsx,
                                             const float* __restrict__ gw,
                                             int rblk, int cblk, float4 acc[4]) {
#pragma unroll 4
    for (int k = 0; k < 64; k += 4) {
        float4 xv[4], wv[4];
#pragma unroll
        for (int i = 0; i < 4; ++i)
            xv[i] = *reinterpret_cast<const float4*>(ldsx + (4 * rblk + i) * XS + k);
#pragma unroll
        for (int d = 0; d < 4; ++d)
            wv[d] = *reinterpret_cast<const float4*>(gw + (k + d) * 64 + 4 * cblk);
#pragma unroll
        for (int i = 0; i < 4; ++i) {
            float xs[4] = {xv[i].x, xv[i].y, xv[i].z, xv[i].w};
#pragma unroll
            for (int d = 0; d < 4; ++d) {
                acc[i].x = fmaf(xs[d], wv[d].x, acc[i].x);
                acc[i].y = fmaf(xs[d], wv[d].y, acc[i].y);
                acc[i].z = fmaf(xs[d], wv[d].z, acc[i].z);
                acc[i].w = fmaf(xs[d], wv[d].w, acc[i].w);
            }
        }
    }
}

// Evolution scan, re-parallelized (R9: evo+lstm+final ~90->~68us, keep):
// EVR=16 rows/block -> 250 blocks; each thread 1 row x 4 cols; FMA order
// bitwise-identical to the original two-k-loop sequence.
__global__ void __launch_bounds__(256) evo_all_kernel(const float* __restrict__ stat,
                                                      const float* __restrict__ thre,
                                                      const float* __restrict__ dyn0,
                                                      float* __restrict__ all_dyn,
                                                      float* __restrict__ diff,
                                                      float* __restrict__ now_final,
                                                      const float* __restrict__ w1) {
    __shared__ float ldsn[EVR * XS];
    __shared__ float ldss[EVR * XS];
    __shared__ float ldsw[128 * 64];
    int row0 = blockIdx.x * EVR;             // kLN = 4000 = 250*16, exact
    int r  = threadIdx.x >> 4;               // 0..15: this thread's row
    int c4 = (threadIdx.x & 15) << 2;        // 4-col group
    *reinterpret_cast<float4*>(ldsn + r * XS + c4) =
        *reinterpret_cast<const float4*>(dyn0 + (size_t)(row0 + r) * 64 + c4);
    stage_w<128>(w1, ldsw);
    __syncthreads();
    {
        float4 x0 = *reinterpret_cast<const float4*>(ldsn + r * XS + c4);
        *reinterpret_cast<float4*>(all_dyn + (size_t)(row0 + r) * 64 + c4) = x0;
    }
#pragma unroll 1
    for (int t = 1; t < kT; ++t) {
        *reinterpret_cast<float4*>(ldss + r * XS + c4) =
            *reinterpret_cast<const float4*>(stat + (size_t)t * kLN * kD
                                             + (size_t)(row0 + r) * 64 + c4);
        __syncthreads();
        float4 acc = {0.f, 0.f, 0.f, 0.f};
#pragma unroll 4
        for (int k = 0; k < 64; k += 4) {        // now-half, w1[0:64]
            float4 xv = *reinterpret_cast<const float4*>(ldsn + r * XS + k);
            float xs[4] = {xv.x, xv.y, xv.z, xv.w};
#pragma unroll
            for (int d = 0; d < 4; ++d) {
                float4 wv = *reinterpret_cast<const float4*>(ldsw + (k + d) * 64 + c4);
                acc.x = fmaf(xs[d], wv.x, acc.x);
                acc.y = fmaf(xs[d], wv.y, acc.y);
                acc.z = fmaf(xs[d], wv.z, acc.z);
                acc.w = fmaf(xs[d], wv.w, acc.w);
            }
        }
#pragma unroll 4
        for (int k = 0; k < 64; k += 4) {        // stat-half, w1[64:128]
            float4 xv = *reinterpret_cast<const float4*>(ldss + r * XS + k);
            float xs[4] = {xv.x, xv.y, xv.z, xv.w};
#pragma unroll
            for (int d = 0; d < 4; ++d) {
                float4 wv = *reinterpret_cast<const float4*>(ldsw + (64 + k + d) * 64 + c4);
                acc.x = fmaf(xs[d], wv.x, acc.x);
                acc.y = fmaf(xs[d], wv.y, acc.y);
                acc.z = fmaf(xs[d], wv.z, acc.z);
                acc.w = fmaf(xs[d], wv.w, acc.w);
            }
        }
        int row = row0 + r;
        float tt = thre[t * kLN + row];
        float4 xn = *reinterpret_cast<const float4*>(ldsn + r * XS + c4);
        float4 nv;
        nv.x = sigf(acc.x * tt + xn.x * (1.f - tt));
        nv.y = sigf(acc.y * tt + xn.y * (1.f - tt));
        nv.z = sigf(acc.z * tt + xn.z * (1.f - tt));
        nv.w = sigf(acc.w * tt + xn.w * (1.f - tt));
        float4 df;
        df.x = nv.x - xn.x; df.y = nv.y - xn.y;
        df.z = nv.z - xn.z; df.w = nv.w - xn.w;
        *reinterpret_cast<float4*>(all_dyn + ((size_t)t * kLN + row) * 64 + c4) = nv;
        *reinterpret_cast<float4*>(diff + ((size_t)(t - 1) * kLN + row) * 64 + c4) = df;
        if (t == kT - 1)
            *reinterpret_cast<float4*>(now_final + (size_t)row * 64 + c4) = nv;
        __syncthreads();   // all reads of ldsn/ldss done before overwrite
        *reinterpret_cast<float4*>(ldsn + r * XS + c4) = nv;
    }
}

// Batched over 6 chains (blockIdx.y = c). Q -> b1[c], XK -> b2[c].
// 128-row tiles, 8 rows/thread register blocking: per k-chunk {8 x (DS) +
// 4 wq (DS) + 4 wk (VMEM)} feeds 256 FMAs — DS/FMA -25%, VMEM/FMA -50% vs
// the 4-row core. FMA order per output element unchanged (absmax-safe).
__global__ void __launch_bounds__(256) gemm_qk(const float* __restrict__ Xdyn,
                                               const float* __restrict__ Xstat,
                                               const float* __restrict__ wq_all,
                                               const float* __restrict__ wk_all,
                                               float* __restrict__ b1,
                                               float* __restrict__ b2, int step) {
    __shared__ float ldsx[128 * XS];
    __shared__ float ldswq[64 * 64];
    int c = blockIdx.y;
    int m = c / 3;
    float* b1c = b1 + (size_t)c * kBUF;
    float* b2c = b2 + (size_t)c * kBUF;
    const float* X = step ? b1c : (m == 0 ? Xdyn : Xstat);
    size_t woff = (size_t)(c * 2 + step) * kD * kD;
    int row0 = blockIdx.x * 128;             // kTLN = 32000 = 250*128, exact
    {   // stage 128x64 tile: 8 float4 per thread
        int r  = threadIdx.x >> 4;
        int c4 = (threadIdx.x & 15) << 2;
#pragma unroll
        for (int i = 0; i < 8; ++i) {
            int rr = r + 16 * i;             // 0..127
            *reinterpret_cast<float4*>(ldsx + rr * XS + c4) =
                *reinterpret_cast<const float4*>(X + (size_t)(row0 + rr) * 64 + c4);
        }
    }
    stage_w<64>(wq_all + woff, ldswq);
    __syncthreads();
    int rblk = threadIdx.x >> 4, cblk = threadIdx.x & 15;
    const float* gwk = wk_all + woff;
    float4 aq[8] = {}, ak[8] = {};
#pragma unroll 2
    for (int k = 0; k < 64; k += 4) {
        float4 wa[4], wb[4];
#pragma unroll
        for (int d = 0; d < 4; ++d) {
            wa[d] = *reinterpret_cast<const float4*>(ldswq + (k + d) * 64 + 4 * cblk);
            wb[d] = *reinterpret_cast<const float4*>(gwk + (k + d) * 64 + 4 * cblk);
        }
#pragma unroll
        for (int i = 0; i < 8; ++i) {
            float4 xv = *reinterpret_cast<const float4*>(ldsx + (8 * rblk + i) * XS + k);
            float xs[4] = {xv.x, xv.y, xv.z, xv.w};
#pragma unroll
            for (int d = 0; d < 4; ++d) {
                aq[i].x = fmaf(xs[d], wa[d].x, aq[i].x);
                aq[i].y = fmaf(xs[d], wa[d].y, aq[i].y);
                aq[i].z = fmaf(xs[d], wa[d].z, aq[i].z);
                aq[i].w = fmaf(xs[d], wa[d].w, aq[i].w);
                ak[i].x = fmaf(xs[d], wb[d].x, ak[i].x);
                ak[i].y = fmaf(xs[d], wb[d].y, ak[i].y);
                ak[i].z = fmaf(xs[d], wb[d].z, ak[i].z);
                ak[i].w = fmaf(xs[d], wb[d].w, ak[i].w);
            }
        }
    }
#pragma unroll
    for (int i = 0; i < 8; ++i) {
        size_t row = row0 + 8 * rblk + i;
        *reinterpret_cast<float4*>(b1c + row * 64 + 4 * cblk) = aq[i];
        *reinterpret_cast<float4*>(b2c + row * 64 + 4 * cblk) = ak[i];
    }
}

// Fused score+softmax+combine+wd, batched over 6 chains, XCD-swizzled.
// UNCHANGED (control kernel: expect ~62.5us; movement = noise).
__global__ void __launch_bounds__(256) scorewd_kernel(float* __restrict__ b1,
                                                      const float* __restrict__ b2,
                                                      const int* __restrict__ npoi,
                                                      const int* __restrict__ nroad,
                                                      const int* __restrict__ nrec,
                                                      const float* __restrict__ wd_all,
                                                      int step) {
    __shared__ float ldsx[64 * XS];
    int p   = blockIdx.y * gridDim.x + blockIdx.x;
    int xcd = p & 7;
    int gid = xcd * 375 + (p >> 3);      // 0..2999
    int c    = gid / 500;
    int tile = gid - c * 500;
    int g = c % 3;
    float* b1c = b1 + (size_t)c * kBUF;
    const float* b2c = b2 + (size_t)c * kBUF;
    const int* neigh = (g == 0) ? npoi : (g == 1) ? nroad : nrec;
    const float* gw = wd_all + (size_t)(c * 2 + step) * kD * kD;

    int lane = threadIdx.x & 63;
    int wv   = threadIdx.x >> 6;
    int sub  = lane >> 4;
    int gq   = lane & 15;
    int row0 = tile * 64;
#pragma unroll 1
    for (int pp = 0; pp < 4; ++pp) {
        int lr  = pp * 16 + wv * 4 + sub;    // local row 0..63
        int row = row0 + lr;
        int n   = row % kN;
        int slab = row - n;
        float4 q = *(reinterpret_cast<const float4*>(b1c) + (size_t)row * 16 + gq);
        const int4* nbp = reinterpret_cast<const int4*>(neigh + n * kK);
        int4 nb0 = nbp[0], nb1 = nbp[1], nb2 = nbp[2];
        int nb[12] = {nb0.x, nb0.y, nb0.z, nb0.w, nb1.x, nb1.y, nb1.z, nb1.w,
                      nb2.x, nb2.y, nb2.z, nb2.w};
        float4 kv[12];
        float sc[12];
#pragma unroll
        for (int j = 0; j < 12; ++j) {
            kv[j] = *(reinterpret_cast<const float4*>(b2c) + (size_t)(slab + nb[j]) * 16 + gq);
            sc[j] = q.x * kv[j].x + q.y * kv[j].y + q.z * kv[j].z + q.w * kv[j].w;
        }
#pragma unroll
        for (int j = 0; j < 12; ++j) sc[j] = row_allreduce16(sc[j]);
        float mx = sc[0];
#pragma unroll
        for (int j = 1; j < 12; ++j) mx = fmaxf(mx, sc[j]);
        float ssum = 0.f;
#pragma unroll
        for (int j = 0; j < 12; ++j) { sc[j] = __expf(sc[j] - mx); ssum += sc[j]; }
        float inv = 1.f / ssum;
        float4 o = q;
#pragma unroll
        for (int j = 0; j < 12; ++j) {
            float a = sc[j] * inv;
            o.x = fmaf(a, kv[j].x, o.x);
            o.y = fmaf(a, kv[j].y, o.y);
            o.z = fmaf(a, kv[j].z, o.z);
            o.w = fmaf(a, kv[j].w, o.w);
        }
        *reinterpret_cast<float4*>(ldsx + lr * XS + 4 * gq) = o;
    }
    __syncthreads();
    int rblk = threadIdx.x >> 4, cblk = threadIdx.x & 15;
    float4 acc[4] = {};
    gemm_core_gw(ldsx, gw, rblk, cblk, acc);
#pragma unroll
    for (int i = 0; i < 4; ++i) {
        size_t idx = ((size_t)(row0 + 4 * rblk + i)) * 64 + 4 * cblk;
        float4 y;
        y.x = sigf(acc[i].x); y.y = sigf(acc[i].y);
        y.z = sigf(acc[i].z); y.w = sigf(acc[i].w);
        *reinterpret_cast<float4*>(b1c + idx) = y;
    }
}

// LSTM with the mix fused in: DPP allreduce for gates, fast-exp tanh.
__global__ void __launch_bounds__(256) lstm_kernel(const float* __restrict__ b1,
                                                   const float* __restrict__ wmix,
                                                   const float* __restrict__ cw,
                                                   const float* __restrict__ cb,
                                                   float* __restrict__ hlast) {
    int lane = threadIdx.x & 63;
    int wv   = threadIdx.x >> 6;
    int sub  = lane >> 4;
    int fq   = lane & 15;
    int cell = blockIdx.x * 16 + wv * 4 + sub;   // 0..3999
    int t = cell / kN, n = cell % kN;
    float wd_[4][4], ws_[4][4], wh[4], bb[4];
#pragma unroll
    for (int gg = 0; gg < 4; ++gg) {
#pragma unroll
        for (int k = 0; k < 4; ++k) {
            wd_[gg][k] = cw[gg * 129 + fq * 4 + k];
            ws_[gg][k] = cw[gg * 129 + 64 + fq * 4 + k];
        }
        wh[gg] = cw[gg * 129 + 128];
        bb[gg] = cb[gg];
    }
    float4 wm[6];
#pragma unroll
    for (int j = 0; j < 6; ++j)
        wm[j] = *reinterpret_cast<const float4*>(wmix + j * 64 + fq * 4);
    float h = 0.f, cc = 0.f;
#pragma unroll 1
    for (int l = 0; l < kL; ++l) {
        size_t row16 = ((size_t)(t * kL + l) * kN + n) * 16 + fq;
        float4 y[6];
#pragma unroll
        for (int j = 0; j < 6; ++j)
            y[j] = *(reinterpret_cast<const float4*>(b1) + (size_t)j * (kBUF / 4) + row16);
        float4 xd, xs;
        xd.x = sigf(y[0].x * wm[0].x + y[1].x * wm[1].x + y[2].x * wm[2].x);
        xd.y = sigf(y[0].y * wm[0].y + y[1].y * wm[1].y + y[2].y * wm[2].y);
        xd.z = sigf(y[0].z * wm[0].z + y[1].z * wm[1].z + y[2].z * wm[2].z);
        xd.w = sigf(y[0].w * wm[0].w + y[1].w * wm[1].w + y[2].w * wm[2].w);
        xs.x = sigf(y[3].x * wm[3].x + y[4].x * wm[4].x + y[5].x * wm[5].x);
        xs.y = sigf(y[3].y * wm[3].y + y[4].y * wm[4].y + y[5].y * wm[5].y);
        xs.z = sigf(y[3].z * wm[3].z + y[4].z * wm[4].z + y[5].z * wm[5].z);
        xs.w = sigf(y[3].w * wm[3].w + y[4].w * wm[4].w + y[5].w * wm[5].w);
        float gsum[4];
#pragma unroll
        for (int gg = 0; gg < 4; ++gg) {
            float v = xd.x * wd_[gg][0] + xd.y * wd_[gg][1]
                    + xd.z * wd_[gg][2] + xd.w * wd_[gg][3];
            v += xs.x * ws_[gg][0] + xs.y * ws_[gg][1]
               + xs.z * ws_[gg][2] + xs.w * ws_[gg][3];
            gsum[gg] = v;
        }
#pragma unroll
        for (int gg = 0; gg < 4; ++gg) gsum[gg] = row_allreduce16(gsum[gg]);
        float gi = sigf(gsum[0] + bb[0] + h * wh[0]);
        float gf = sigf(gsum[1] + bb[1] + h * wh[1]);
        float go = sigf(gsum[2] + bb[2] + h * wh[2]);
        float gg_ = tanh_fast(gsum[3] + bb[3] + h * wh[3]);
        cc = gf * cc + gi * gg_;
        h = go * tanh_fast(cc);
    }
    if (fq == 0) hlast[cell] = h;
}

// out[t,m] = sigmoid(sum_n h[t,n]*fw[m,n] + fb[m]); one wave per output.
__global__ void final_kernel(const float* __restrict__ h, const float* __restrict__ fw,
                             const float* __restrict__ fb, float* __restrict__ out) {
    int wave = threadIdx.x >> 6, lane = threadIdx.x & 63;
    int o = blockIdx.x * 4 + wave;
    int t = o / kN, m = o % kN;
    float acc = 0.f;
    for (int n = lane; n < kN; n += 64)
        acc = fmaf(h[t * kN + n], fw[(size_t)m * kN + n], acc);
#pragma unroll
    for (int off = 32; off > 0; off >>= 1) acc += __shfl_xor(acc, off);
    if (lane == 0) out[o] = sigf(acc + fb[m]);
}

extern "C" void kernel_launch(void* const* d_in, const int* in_sizes, int n_in,
                              void* d_out, int out_size, void* d_ws, size_t ws_size,
                              hipStream_t stream) {
    const float* stat   = (const float*)d_in[0];
    const float* thre   = (const float*)d_in[1];
    const float* dyn0   = (const float*)d_in[2];
    const int*   npoi   = (const int*)d_in[3];
    const int*   nroad  = (const int*)d_in[4];
    const int*   nrec   = (const int*)d_in[5];
    const float* w1     = (const float*)d_in[6];
    const float* wq_all = (const float*)d_in[7];
    const float* wk_all = (const float*)d_in[8];
    const float* wd_all = (const float*)d_in[9];
    const float* wmix   = (const float*)d_in[10];
    const float* conv_w = (const float*)d_in[11];
    const float* conv_b = (const float*)d_in[12];
    const float* fin_w  = (const float*)d_in[13];
    const float* fin_b  = (const float*)d_in[14];

    float* out       = (float*)d_out;                 // (T,N)
    float* now_final = out + kT * kN;                 // (L,N,D)
    float* diffs     = now_final + (size_t)kLN * kD;  // (T-1,L,N,D)

    float* ws      = (float*)d_ws;
    float* all_dyn = ws;                              // (T,L,N,D)
    float* b1      = ws + (size_t)kBUF;               // 6 x Q/y chain buffers
    float* b2      = ws + 7 * (size_t)kBUF;           // 6 x XK buffers
    float* hlast   = ws + 13 * (size_t)kBUF;          // (T,N)

    // ---- evolution scan: 250 blocks (16 independent rows each) ----
    evo_all_kernel<<<kLN / EVR, 256, 0, stream>>>(stat, thre, dyn0,
                                                  all_dyn, diffs, now_final, w1);

    // ---- attention: 6 chains batched, 2 steps ----
    dim3 ggrid(kTLN / 128, 6);   // gemm_qk: 128-row tiles
    dim3 sgrid(kTLN / 64, 6);    // scorewd: 64-row tiles (unchanged)
    gemm_qk<<<ggrid, 256, 0, stream>>>(all_dyn, stat, wq_all, wk_all, b1, b2, 0);
    scorewd_kernel<<<sgrid, 256, 0, stream>>>(b1, b2, npoi, nroad, nrec, wd_all, 0);
    gemm_qk<<<ggrid, 256, 0, stream>>>(all_dyn, stat, wq_all, wk_all, b1, b2, 1);
    scorewd_kernel<<<sgrid, 256, 0, stream>>>(b1, b2, npoi, nroad, nrec, wd_all, 1);

    // ---- LSTM (mix fused) over l, then final projection ----
    lstm_kernel<<<kT * kN / 16, 256, 0, stream>>>(b1, wmix, conv_w, conv_b, hlast);
    final_kernel<<<kT * kN / 4, 256, 0, stream>>>(hlast, fin_w, fin_b, out);
}

// Round 13
// 304.848 us; speedup vs baseline: 1.0504x; 1.0504x over previous
//
#include <hip/hip_runtime.h>
#include <math.h>

namespace {
constexpr int kT = 8, kL = 8, kN = 500, kD = 64, kK = 12;
constexpr int kLN  = kL * kN;        // 4000
constexpr int kTLN = kT * kL * kN;   // 32000
constexpr int kBUF = kTLN * kD;      // 2,048,000 floats
constexpr int XS = 68;               // padded LDS stride for X tiles
constexpr int EVR = 16;              // evo rows per block -> 250 blocks
}

__device__ __forceinline__ float sigf(float v) { return 1.f / (1.f + __expf(-v)); }

// Overflow-safe fast tanh: one v_exp instead of libm tanhf's long sequence.
__device__ __forceinline__ float tanh_fast(float v) {
    float e = __expf(-2.f * fabsf(v));
    float t = (1.f - e) / (1.f + e);
    return copysignf(t, v);
}

// 16-lane allreduce (sum) entirely on the VALU pipe via DPP — no DS ops.
// (validated R4: scorewd VALUBusy 53->65%, total -20us)
__device__ __forceinline__ float row_allreduce16(float v) {
    v += __int_as_float(__builtin_amdgcn_update_dpp(
            0, __float_as_int(v), 0xB1, 0xf, 0xf, true));   // quad_perm [1,0,3,2]
    v += __int_as_float(__builtin_amdgcn_update_dpp(
            0, __float_as_int(v), 0x4E, 0xf, 0xf, true));   // quad_perm [2,3,0,1]
    v += __int_as_float(__builtin_amdgcn_update_dpp(
            0, __float_as_int(v), 0x124, 0xf, 0xf, true));  // row_ror:4
    v += __int_as_float(__builtin_amdgcn_update_dpp(
            0, __float_as_int(v), 0x128, 0xf, 0xf, true));  // row_ror:8
    return v;
}

// Stage a 64x64 f32 tile (global row stride 64) into LDS (stride XS).
__device__ __forceinline__ void stage_x(const float* __restrict__ src, float* lds,
                                        int row0) {
    int r  = threadIdx.x >> 4;
    int c4 = (threadIdx.x & 15) << 2;
#pragma unroll
    for (int i = 0; i < 4; ++i) {
        int rr  = r + 16 * i;
        float4 v = *reinterpret_cast<const float4*>(src + (size_t)(row0 + rr) * 64 + c4);
        *reinterpret_cast<float4*>(lds + rr * XS + c4) = v;
    }
}

// Stage K x 64 weight (row-major) into LDS, stride 64.
template <int K>
__device__ __forceinline__ void stage_w(const float* __restrict__ w, float* lds) {
    const float4* s = reinterpret_cast<const float4*>(w);
    float4* d = reinterpret_cast<float4*>(lds);
#pragma unroll
    for (int i = 0; i < K / 16; ++i)
        d[threadIdx.x + 256 * i] = s[threadIdx.x + 256 * i];
}

// acc[i] += row(4*rblk+i) of Xtile @ W[:, 4*cblk..+3], K=64; W from global
// (L1-resident). Splits traffic: x on the DS pipe, w on the VMEM pipe.
__device__ __forceinline__ void gemm_core_gw(const float* ldsx,
                                             const float* __restrict__ gw,
                                             int rblk, int cblk, float4 acc[4]) {
#pragma unroll 4
    for (int k = 0; k < 64; k += 4) {
        float4 xv[4], wv[4];
#pragma unroll
        for (int i = 0; i < 4; ++i)
            xv[i] = *reinterpret_cast<const float4*>(ldsx + (4 * rblk + i) * XS + k);
#pragma unroll
        for (int d = 0; d < 4; ++d)
            wv[d] = *reinterpret_cast<const float4*>(gw + (k + d) * 64 + 4 * cblk);
#pragma unroll
        for (int i = 0; i < 4; ++i) {
            float xs[4] = {xv[i].x, xv[i].y, xv[i].z, xv[i].w};
#pragma unroll
            for (int d = 0; d < 4; ++d) {
                acc[i].x = fmaf(xs[d], wv[d].x, acc[i].x);
                acc[i].y = fmaf(xs[d], wv[d].y, acc[i].y);
                acc[i].z = fmaf(xs[d], wv[d].z, acc[i].z);
                acc[i].w = fmaf(xs[d], wv[d].w, acc[i].w);
            }
        }
    }
}

// BALANCED two-weight core: x + wa from LDS (DS pipe), wb from global (VMEM
// pipe). R9/R10 measured: all-global 74us, balanced 62us (best).
__device__ __forceinline__ void gemm_core2_bal(const float* ldsx, const float* ldswa,
                                               const float* __restrict__ gwb,
                                               int rblk, int cblk,
                                               float4 acca[4], float4 accb[4]) {
#pragma unroll 4
    for (int k = 0; k < 64; k += 4) {
        float4 xv[4], wa[4], wb[4];
#pragma unroll
        for (int i = 0; i < 4; ++i)
            xv[i] = *reinterpret_cast<const float4*>(ldsx + (4 * rblk + i) * XS + k);
#pragma unroll
        for (int d = 0; d < 4; ++d) {
            wa[d] = *reinterpret_cast<const float4*>(ldswa + (k + d) * 64 + 4 * cblk);
            wb[d] = *reinterpret_cast<const float4*>(gwb + (k + d) * 64 + 4 * cblk);
        }
#pragma unroll
        for (int i = 0; i < 4; ++i) {
            float xs[4] = {xv[i].x, xv[i].y, xv[i].z, xv[i].w};
#pragma unroll
            for (int d = 0; d < 4; ++d) {
                acca[i].x = fmaf(xs[d], wa[d].x, acca[i].x);
                acca[i].y = fmaf(xs[d], wa[d].y, acca[i].y);
                acca[i].z = fmaf(xs[d], wa[d].z, acca[i].z);
                acca[i].w = fmaf(xs[d], wa[d].w, acca[i].w);
                accb[i].x = fmaf(xs[d], wb[d].x, accb[i].x);
                accb[i].y = fmaf(xs[d], wb[d].y, accb[i].y);
                accb[i].z = fmaf(xs[d], wb[d].z, accb[i].z);
                accb[i].w = fmaf(xs[d], wb[d].w, accb[i].w);
            }
        }
    }
}

// gemm_qk body on a 64-row tile (R10 best structure): x+wq in LDS, wk global.
__device__ __forceinline__ void gemm_qk_body(const float* __restrict__ X,
                                             const float* __restrict__ wq,
                                             const float* __restrict__ wk,
                                             float* __restrict__ b1c,
                                             float* __restrict__ b2c,
                                             int row0, float* ldsx, float* ldswq) {
    stage_x(X, ldsx, row0);
    stage_w<64>(wq, ldswq);
    __syncthreads();
    int rblk = threadIdx.x >> 4, cblk = threadIdx.x & 15;
    float4 aq[4] = {}, ak[4] = {};
    gemm_core2_bal(ldsx, ldswq, wk, rblk, cblk, aq, ak);
#pragma unroll
    for (int i = 0; i < 4; ++i) {
        size_t row = row0 + 4 * rblk + i;
        *reinterpret_cast<float4*>(b1c + row * 64 + 4 * cblk) = aq[i];
        *reinterpret_cast<float4*>(b2c + row * 64 + 4 * cblk) = ak[i];
    }
}

// COMBINED: evo (blocks 0..249, latency-bound serial t-loop, fills ~12% of
// wave slots alone) + stat-chain gemm_qk step0 (blocks 250..1749, chains 3-5,
// which read `stat` directly and have NO dependence on evo). The gemm blocks
// fill the CUs evo leaves idle: ~max(25,31)us instead of 25+31 serial.
__global__ void __launch_bounds__(256) evo_statqk_kernel(
        const float* __restrict__ stat, const float* __restrict__ thre,
        const float* __restrict__ dyn0, float* __restrict__ all_dyn,
        float* __restrict__ diff, float* __restrict__ now_final,
        const float* __restrict__ w1, const float* __restrict__ wq_all,
        const float* __restrict__ wk_all, float* __restrict__ b1,
        float* __restrict__ b2) {
    __shared__ float lds[2 * EVR * XS + 128 * 64];   // 10368 floats = 41.5KB
    if (blockIdx.x < kLN / EVR) {
        // ---------------- evo path ----------------
        float* ldsn = lds;
        float* ldss = lds + EVR * XS;
        float* ldsw = lds + 2 * EVR * XS;
        int row0 = blockIdx.x * EVR;
        int r  = threadIdx.x >> 4;
        int c4 = (threadIdx.x & 15) << 2;
        *reinterpret_cast<float4*>(ldsn + r * XS + c4) =
            *reinterpret_cast<const float4*>(dyn0 + (size_t)(row0 + r) * 64 + c4);
        stage_w<128>(w1, ldsw);
        __syncthreads();
        {
            float4 x0 = *reinterpret_cast<const float4*>(ldsn + r * XS + c4);
            *reinterpret_cast<float4*>(all_dyn + (size_t)(row0 + r) * 64 + c4) = x0;
        }
#pragma unroll 1
        for (int t = 1; t < kT; ++t) {
            *reinterpret_cast<float4*>(ldss + r * XS + c4) =
                *reinterpret_cast<const float4*>(stat + (size_t)t * kLN * kD
                                                 + (size_t)(row0 + r) * 64 + c4);
            __syncthreads();
            float4 acc = {0.f, 0.f, 0.f, 0.f};
#pragma unroll 4
            for (int k = 0; k < 64; k += 4) {        // now-half, w1[0:64]
                float4 xv = *reinterpret_cast<const float4*>(ldsn + r * XS + k);
                float xs[4] = {xv.x, xv.y, xv.z, xv.w};
#pragma unroll
                for (int d = 0; d < 4; ++d) {
                    float4 wv = *reinterpret_cast<const float4*>(ldsw + (k + d) * 64 + c4);
                    acc.x = fmaf(xs[d], wv.x, acc.x);
                    acc.y = fmaf(xs[d], wv.y, acc.y);
                    acc.z = fmaf(xs[d], wv.z, acc.z);
                    acc.w = fmaf(xs[d], wv.w, acc.w);
                }
            }
#pragma unroll 4
            for (int k = 0; k < 64; k += 4) {        // stat-half, w1[64:128]
                float4 xv = *reinterpret_cast<const float4*>(ldss + r * XS + k);
                float xs[4] = {xv.x, xv.y, xv.z, xv.w};
#pragma unroll
                for (int d = 0; d < 4; ++d) {
                    float4 wv = *reinterpret_cast<const float4*>(ldsw + (64 + k + d) * 64 + c4);
                    acc.x = fmaf(xs[d], wv.x, acc.x);
                    acc.y = fmaf(xs[d], wv.y, acc.y);
                    acc.z = fmaf(xs[d], wv.z, acc.z);
                    acc.w = fmaf(xs[d], wv.w, acc.w);
                }
            }
            int row = row0 + r;
            float tt = thre[t * kLN + row];
            float4 xn = *reinterpret_cast<const float4*>(ldsn + r * XS + c4);
            float4 nv;
            nv.x = sigf(acc.x * tt + xn.x * (1.f - tt));
            nv.y = sigf(acc.y * tt + xn.y * (1.f - tt));
            nv.z = sigf(acc.z * tt + xn.z * (1.f - tt));
            nv.w = sigf(acc.w * tt + xn.w * (1.f - tt));
            float4 df;
            df.x = nv.x - xn.x; df.y = nv.y - xn.y;
            df.z = nv.z - xn.z; df.w = nv.w - xn.w;
            *reinterpret_cast<float4*>(all_dyn + ((size_t)t * kLN + row) * 64 + c4) = nv;
            *reinterpret_cast<float4*>(diff + ((size_t)(t - 1) * kLN + row) * 64 + c4) = df;
            if (t == kT - 1)
                *reinterpret_cast<float4*>(now_final + (size_t)row * 64 + c4) = nv;
            __syncthreads();
            *reinterpret_cast<float4*>(ldsn + r * XS + c4) = nv;
        }
    } else {
        // ---------------- stat-chain gemm_qk (step 0, chains 3..5) ----------
        int b = blockIdx.x - kLN / EVR;
        int c = 3 + b / 500;
        int tile = b - (c - 3) * 500;
        float* b1c = b1 + (size_t)c * kBUF;
        float* b2c = b2 + (size_t)c * kBUF;
        size_t woff = (size_t)(c * 2) * kD * kD;
        gemm_qk_body(stat, wq_all + woff, wk_all + woff, b1c, b2c,
                     tile * 64, lds, lds + 64 * XS);
    }
}

// gemm_qk dispatch: c = cbase + blockIdx.y. step0-dyn: cbase=0, gridy=3.
// step1: cbase=0, gridy=6. (R10 best 64-row balanced structure.)
__global__ void __launch_bounds__(256) gemm_qk(const float* __restrict__ Xdyn,
                                               const float* __restrict__ Xstat,
                                               const float* __restrict__ wq_all,
                                               const float* __restrict__ wk_all,
                                               float* __restrict__ b1,
                                               float* __restrict__ b2, int step) {
    __shared__ float ldsx[64 * XS];
    __shared__ float ldswq[64 * 64];
    int c = blockIdx.y;
    int m = c / 3;
    float* b1c = b1 + (size_t)c * kBUF;
    float* b2c = b2 + (size_t)c * kBUF;
    const float* X = step ? b1c : (m == 0 ? Xdyn : Xstat);
    size_t woff = (size_t)(c * 2 + step) * kD * kD;
    gemm_qk_body(X, wq_all + woff, wk_all + woff, b1c, b2c,
                 blockIdx.x * 64, ldsx, ldswq);
}

// Fused score+softmax+combine+wd, batched over 6 chains, XCD-swizzled.
// UNCHANGED (control kernel: expect ~63us; movement = noise).
__global__ void __launch_bounds__(256) scorewd_kernel(float* __restrict__ b1,
                                                      const float* __restrict__ b2,
                                                      const int* __restrict__ npoi,
                                                      const int* __restrict__ nroad,
                                                      const int* __restrict__ nrec,
                                                      const float* __restrict__ wd_all,
                                                      int step) {
    __shared__ float ldsx[64 * XS];
    int p   = blockIdx.y * gridDim.x + blockIdx.x;
    int xcd = p & 7;
    int gid = xcd * 375 + (p >> 3);      // 0..2999
    int c    = gid / 500;
    int tile = gid - c * 500;
    int g = c % 3;
    float* b1c = b1 + (size_t)c * kBUF;
    const float* b2c = b2 + (size_t)c * kBUF;
    const int* neigh = (g == 0) ? npoi : (g == 1) ? nroad : nrec;
    const float* gw = wd_all + (size_t)(c * 2 + step) * kD * kD;

    int lane = threadIdx.x & 63;
    int wv   = threadIdx.x >> 6;
    int sub  = lane >> 4;
    int gq   = lane & 15;
    int row0 = tile * 64;
#pragma unroll 1
    for (int pp = 0; pp < 4; ++pp) {
        int lr  = pp * 16 + wv * 4 + sub;    // local row 0..63
        int row = row0 + lr;
        int n   = row % kN;
        int slab = row - n;
        float4 q = *(reinterpret_cast<const float4*>(b1c) + (size_t)row * 16 + gq);
        const int4* nbp = reinterpret_cast<const int4*>(neigh + n * kK);
        int4 nb0 = nbp[0], nb1 = nbp[1], nb2 = nbp[2];
        int nb[12] = {nb0.x, nb0.y, nb0.z, nb0.w, nb1.x, nb1.y, nb1.z, nb1.w,
                      nb2.x, nb2.y, nb2.z, nb2.w};
        float4 kv[12];
        float sc[12];
#pragma unroll
        for (int j = 0; j < 12; ++j) {
            kv[j] = *(reinterpret_cast<const float4*>(b2c) + (size_t)(slab + nb[j]) * 16 + gq);
            sc[j] = q.x * kv[j].x + q.y * kv[j].y + q.z * kv[j].z + q.w * kv[j].w;
        }
#pragma unroll
        for (int j = 0; j < 12; ++j) sc[j] = row_allreduce16(sc[j]);
        float mx = sc[0];
#pragma unroll
        for (int j = 1; j < 12; ++j) mx = fmaxf(mx, sc[j]);
        float ssum = 0.f;
#pragma unroll
        for (int j = 0; j < 12; ++j) { sc[j] = __expf(sc[j] - mx); ssum += sc[j]; }
        float inv = 1.f / ssum;
        float4 o = q;
#pragma unroll
        for (int j = 0; j < 12; ++j) {
            float a = sc[j] * inv;
            o.x = fmaf(a, kv[j].x, o.x);
            o.y = fmaf(a, kv[j].y, o.y);
            o.z = fmaf(a, kv[j].z, o.z);
            o.w = fmaf(a, kv[j].w, o.w);
        }
        *reinterpret_cast<float4*>(ldsx + lr * XS + 4 * gq) = o;
    }
    __syncthreads();
    int rblk = threadIdx.x >> 4, cblk = threadIdx.x & 15;
    float4 acc[4] = {};
    gemm_core_gw(ldsx, gw, rblk, cblk, acc);
#pragma unroll
    for (int i = 0; i < 4; ++i) {
        size_t idx = ((size_t)(row0 + 4 * rblk + i)) * 64 + 4 * cblk;
        float4 y;
        y.x = sigf(acc[i].x); y.y = sigf(acc[i].y);
        y.z = sigf(acc[i].z); y.w = sigf(acc[i].w);
        *reinterpret_cast<float4*>(b1c + idx) = y;
    }
}

// LSTM with the mix fused in: DPP allreduce for gates, fast-exp tanh.
__global__ void __launch_bounds__(256) lstm_kernel(const float* __restrict__ b1,
                                                   const float* __restrict__ wmix,
                                                   const float* __restrict__ cw,
                                                   const float* __restrict__ cb,
                                                   float* __restrict__ hlast) {
    int lane = threadIdx.x & 63;
    int wv   = threadIdx.x >> 6;
    int sub  = lane >> 4;
    int fq   = lane & 15;
    int cell = blockIdx.x * 16 + wv * 4 + sub;   // 0..3999
    int t = cell / kN, n = cell % kN;
    float wd_[4][4], ws_[4][4], wh[4], bb[4];
#pragma unroll
    for (int gg = 0; gg < 4; ++gg) {
#pragma unroll
        for (int k = 0; k < 4; ++k) {
            wd_[gg][k] = cw[gg * 129 + fq * 4 + k];
            ws_[gg][k] = cw[gg * 129 + 64 + fq * 4 + k];
        }
        wh[gg] = cw[gg * 129 + 128];
        bb[gg] = cb[gg];
    }
    float4 wm[6];
#pragma unroll
    for (int j = 0; j < 6; ++j)
        wm[j] = *reinterpret_cast<const float4*>(wmix + j * 64 + fq * 4);
    float h = 0.f, cc = 0.f;
#pragma unroll 1
    for (int l = 0; l < kL; ++l) {
        size_t row16 = ((size_t)(t * kL + l) * kN + n) * 16 + fq;
        float4 y[6];
#pragma unroll
        for (int j = 0; j < 6; ++j)
            y[j] = *(reinterpret_cast<const float4*>(b1) + (size_t)j * (kBUF / 4) + row16);
        float4 xd, xs;
        xd.x = sigf(y[0].x * wm[0].x + y[1].x * wm[1].x + y[2].x * wm[2].x);
        xd.y = sigf(y[0].y * wm[0].y + y[1].y * wm[1].y + y[2].y * wm[2].y);
        xd.z = sigf(y[0].z * wm[0].z + y[1].z * wm[1].z + y[2].z * wm[2].z);
        xd.w = sigf(y[0].w * wm[0].w + y[1].w * wm[1].w + y[2].w * wm[2].w);
        xs.x = sigf(y[3].x * wm[3].x + y[4].x * wm[4].x + y[5].x * wm[5].x);
        xs.y = sigf(y[3].y * wm[3].y + y[4].y * wm[4].y + y[5].y * wm[5].y);
        xs.z = sigf(y[3].z * wm[3].z + y[4].z * wm[4].z + y[5].z * wm[5].z);
        xs.w = sigf(y[3].w * wm[3].w + y[4].w * wm[4].w + y[5].w * wm[5].w);
        float gsum[4];
#pragma unroll
        for (int gg = 0; gg < 4; ++gg) {
            float v = xd.x * wd_[gg][0] + xd.y * wd_[gg][1]
                    + xd.z * wd_[gg][2] + xd.w * wd_[gg][3];
            v += xs.x * ws_[gg][0] + xs.y * ws_[gg][1]
               + xs.z * ws_[gg][2] + xs.w * ws_[gg][3];
            gsum[gg] = v;
        }
#pragma unroll
        for (int gg = 0; gg < 4; ++gg) gsum[gg] = row_allreduce16(gsum[gg]);
        float gi = sigf(gsum[0] + bb[0] + h * wh[0]);
        float gf = sigf(gsum[1] + bb[1] + h * wh[1]);
        float go = sigf(gsum[2] + bb[2] + h * wh[2]);
        float gg_ = tanh_fast(gsum[3] + bb[3] + h * wh[3]);
        cc = gf * cc + gi * gg_;
        h = go * tanh_fast(cc);
    }
    if (fq == 0) hlast[cell] = h;
}

// out[t,m] = sigmoid(sum_n h[t,n]*fw[m,n] + fb[m]); one wave per output.
__global__ void final_kernel(const float* __restrict__ h, const float* __restrict__ fw,
                             const float* __restrict__ fb, float* __restrict__ out) {
    int wave = threadIdx.x >> 6, lane = threadIdx.x & 63;
    int o = blockIdx.x * 4 + wave;
    int t = o / kN, m = o % kN;
    float acc = 0.f;
    for (int n = lane; n < kN; n += 64)
        acc = fmaf(h[t * kN + n], fw[(size_t)m * kN + n], acc);
#pragma unroll
    for (int off = 32; off > 0; off >>= 1) acc += __shfl_xor(acc, off);
    if (lane == 0) out[o] = sigf(acc + fb[m]);
}

extern "C" void kernel_launch(void* const* d_in, const int* in_sizes, int n_in,
                              void* d_out, int out_size, void* d_ws, size_t ws_size,
                              hipStream_t stream) {
    const float* stat   = (const float*)d_in[0];
    const float* thre   = (const float*)d_in[1];
    const float* dyn0   = (const float*)d_in[2];
    const int*   npoi   = (const int*)d_in[3];
    const int*   nroad  = (const int*)d_in[4];
    const int*   nrec   = (const int*)d_in[5];
    const float* w1     = (const float*)d_in[6];
    const float* wq_all = (const float*)d_in[7];
    const float* wk_all = (const float*)d_in[8];
    const float* wd_all = (const float*)d_in[9];
    const float* wmix   = (const float*)d_in[10];
    const float* conv_w = (const float*)d_in[11];
    const float* conv_b = (const float*)d_in[12];
    const float* fin_w  = (const float*)d_in[13];
    const float* fin_b  = (const float*)d_in[14];

    float* out       = (float*)d_out;                 // (T,N)
    float* now_final = out + kT * kN;                 // (L,N,D)
    float* diffs     = now_final + (size_t)kLN * kD;  // (T-1,L,N,D)

    float* ws      = (float*)d_ws;
    float* all_dyn = ws;                              // (T,L,N,D)
    float* b1      = ws + (size_t)kBUF;               // 6 x Q/y chain buffers
    float* b2      = ws + 7 * (size_t)kBUF;           // 6 x XK buffers
    float* hlast   = ws + 13 * (size_t)kBUF;          // (T,N)

    // ---- evo (250 blocks) + stat-chain QK step0 (1500 blocks), one dispatch:
    //      the gemm blocks fill CUs the latency-bound evo loop leaves idle ----
    evo_statqk_kernel<<<kLN / EVR + 1500, 256, 0, stream>>>(
        stat, thre, dyn0, all_dyn, diffs, now_final, w1, wq_all, wk_all, b1, b2);

    // ---- dyn-chain QK step0 (depends on evo), then scorewd/QK1/scorewd ----
    dim3 dgrid(500, 3);          // chains 0..2 (dyn)
    dim3 agrid(500, 6);          // all 6 chains
    gemm_qk<<<dgrid, 256, 0, stream>>>(all_dyn, stat, wq_all, wk_all, b1, b2, 0);
    scorewd_kernel<<<agrid, 256, 0, stream>>>(b1, b2, npoi, nroad, nrec, wd_all, 0);
    gemm_qk<<<agrid, 256, 0, stream>>>(all_dyn, stat, wq_all, wk_all, b1, b2, 1);
    scorewd_kernel<<<agrid, 256, 0, stream>>>(b1, b2, npoi, nroad, nrec, wd_all, 1);

    // ---- LSTM (mix fused) over l, then final projection ----
    lstm_kernel<<<kT * kN / 16, 256, 0, stream>>>(b1, wmix, conv_w, conv_b, hlast);
    final_kernel<<<kT * kN / 4, 256, 0, stream>>>(hlast, fin_w, fin_b, out);
}